// Round 5
// baseline (298.908 us; speedup 1.0000x reference)
//
#include <hip/hip_runtime.h>

#define NSER 65536
#define NT   1024
#define SEAS 24
#define SLEN (NT + SEAS)   // 1048 seasonal output columns
#define NW   43            // windows w=0..42; last covers t=1008..1023 (16 steps)

__device__ __forceinline__ float frcp(float x) { return __builtin_amdgcn_rcpf(x); }

// One 32-lane group per TWO series (A/B interleaved for ILP on the shuffle
// chain). Lane j handles timestep t = 24*w + j (j < 24) of both series.
// Level recurrence is linear: lev_t = ia*lev_{t-1} + a*y_t/s_t; with window
// == SEASONALITY the seasonal feedback s_t = ns_{t-24} is LANE-LOCAL.
// Window 0 folds the reference's t=0 special step via lane-0 overrides
// (a_eff=1 -> lev0 = y0/s0; b_eff=0 -> "ns_0" = s0[0], which fills
// seasonalities col 24 and feeds s_24 = s0[0] for window 1).
__global__ __launch_bounds__(256) void es_scan2_kernel(
    const float* __restrict__ y,
    const int*   __restrict__ idxs,
    const float* __restrict__ lev_sms,
    const float* __restrict__ seas_sms,
    const float* __restrict__ init_seas,
    float* __restrict__ levels,
    float* __restrict__ seasout)
{
    const int tid = threadIdx.x;
    const int grp = tid >> 5;                  // 8 groups per block
    const int j   = tid & 31;                  // lane in group; j<24 active
    const bool act = (j < SEAS);

    const int iA = blockIdx.x * 16 + grp * 2;  // two series per group
    const int iB = iA + 1;

    const int idA = idxs[iA];
    const int idB = idxs[iB];

    const float aA  = 1.0f / (1.0f + __expf(-lev_sms[idA]));
    const float bA  = 1.0f / (1.0f + __expf(-seas_sms[idA]));
    const float aB  = 1.0f / (1.0f + __expf(-lev_sms[idB]));
    const float bB  = 1.0f / (1.0f + __expf(-seas_sms[idB]));
    const float iaA = 1.0f - aA, ibA = 1.0f - bA;
    const float iaB = 1.0f - aB, ibB = 1.0f - bB;

    // scan-round weights ia^{1,2,4,8,16} and per-lane carry weight ia^(j+1)
    const float a1A = iaA, a2A = a1A*a1A, a4A = a2A*a2A, a8A = a4A*a4A, a16A = a8A*a8A;
    const float a1B = iaB, a2B = a1B*a1B, a4B = a2B*a2B, a8B = a4B*a4B, a16B = a8B*a8B;
    const float powA = __powf(iaA, (float)(j + 1));
    const float powB = __powf(iaB, (float)(j + 1));

    const size_t lrowA = (size_t)iA * NT,   lrowB = (size_t)iB * NT;
    const size_t srowA = (size_t)iA * SLEN, srowB = (size_t)iB * SLEN;
    const float* yrowA = y + lrowA;
    const float* yrowB = y + lrowB;

    // initial seasonal state s = exp(init_seas[id][j]); emit cols 0..23
    float sA = 1.0f, sB = 1.0f;
    if (act) {
        sA = __expf(init_seas[(size_t)idA * SEAS + j]);
        sB = __expf(init_seas[(size_t)idB * SEAS + j]);
        seasout[srowA + j] = sA;
        seasout[srowB + j] = sB;
    }

    float levpA = 0.0f, levpB = 0.0f;

    // 1-deep y pipeline: window w's data loaded before window w-1's chain ends
    float ytA = 1.0f, ytB = 1.0f;
    if (act) { ytA = yrowA[j]; ytB = yrowB[j]; }

    for (int w = 0; w < NW; ++w) {
        const int t  = SEAS * w + j;
        const bool on = act && (t < NT);

        // prefetch next window's y (independent of this window's chain)
        float ynA = 1.0f, ynB = 1.0f;
        const int tn = t + SEAS;
        if (act && tn < NT) { ynA = yrowA[tn]; ynB = yrowB[tn]; }

        // window-0 lane-0 overrides (the reference's t=0 special step)
        float aeA = aA, beA = bA, ieA = ibA;
        float aeB = aB, beB = bB, ieB = ibB;
        if (w == 0 && j == 0) {
            aeA = 1.0f; beA = 0.0f; ieA = 1.0f;
            aeB = 1.0f; beB = 0.0f; ieB = 1.0f;
        }

        // c_j = a*y/s; weighted inclusive scan: x_j = sum_{m<=j} ia^{j-m} c_m
        float xA = aeA * ytA * frcp(sA);
        float xB = aeB * ytB * frcp(sB);
        float tsA, tsB;
        tsA = __shfl_up(xA, 1, 32);  tsB = __shfl_up(xB, 1, 32);
        if (j >= 1)  { xA = fmaf(a1A,  tsA, xA); xB = fmaf(a1B,  tsB, xB); }
        tsA = __shfl_up(xA, 2, 32);  tsB = __shfl_up(xB, 2, 32);
        if (j >= 2)  { xA = fmaf(a2A,  tsA, xA); xB = fmaf(a2B,  tsB, xB); }
        tsA = __shfl_up(xA, 4, 32);  tsB = __shfl_up(xB, 4, 32);
        if (j >= 4)  { xA = fmaf(a4A,  tsA, xA); xB = fmaf(a4B,  tsB, xB); }
        tsA = __shfl_up(xA, 8, 32);  tsB = __shfl_up(xB, 8, 32);
        if (j >= 8)  { xA = fmaf(a8A,  tsA, xA); xB = fmaf(a8B,  tsB, xB); }
        tsA = __shfl_up(xA, 16, 32); tsB = __shfl_up(xB, 16, 32);
        if (j >= 16) { xA = fmaf(a16A, tsA, xA); xB = fmaf(a16B, tsB, xB); }

        const float levA = fmaf(powA, levpA, xA);
        const float levB = fmaf(powB, levpB, xB);
        const float nsA  = fmaf(ieA, sA, beA * ytA * frcp(levA));
        const float nsB  = fmaf(ieB, sB, beB * ytB * frcp(levB));

        if (on) {
            levels[lrowA + t]         = levA;   // 24 consecutive floats / series
            levels[lrowB + t]         = levB;
            seasout[srowA + SEAS + t] = nsA;
            seasout[srowB + SEAS + t] = nsB;
        }

        levpA = __shfl(levA, 23, 32);   // carry: consumed at END of next scan,
        levpB = __shfl(levB, 23, 32);   // so broadcast overlaps next 5 rounds
        sA = nsA; sB = nsB;             // lane-local seasonal feedback
        ytA = ynA; ytB = ynB;
    }
}

extern "C" void kernel_launch(void* const* d_in, const int* in_sizes, int n_in,
                              void* d_out, int out_size, void* d_ws, size_t ws_size,
                              hipStream_t stream) {
    const float* y         = (const float*)d_in[0];
    const int*   idxs      = (const int*)d_in[1];
    const float* lev_sms   = (const float*)d_in[2];
    const float* seas_sms  = (const float*)d_in[3];
    const float* init_seas = (const float*)d_in[4];

    float* levels  = (float*)d_out;
    float* seasout = levels + (size_t)NSER * NT;

    es_scan2_kernel<<<NSER/16, 256, 0, stream>>>(y, idxs, lev_sms, seas_sms, init_seas,
                                                 levels, seasout);
}

// Round 6
// 264.128 us; speedup vs baseline: 1.1317x; 1.1317x over previous
//
#include <hip/hip_runtime.h>

#define NSER 65536
#define NT   1024
#define SEAS 24
#define SLEN (NT + SEAS)   // 1048 seasonal output columns
#define NW   43            // windows w=0..42; last covers t=1008..1023 (16 steps)

__device__ __forceinline__ float frcp(float x) { return __builtin_amdgcn_rcpf(x); }

// One 32-lane group per series. Lane j handles timestep t = 24*w + j (j < 24).
// Level recurrence is linear: lev_t = ia*lev_{t-1} + a*y_t/s_t; with window
// == SEASONALITY the seasonal feedback s_t = ns_{t-24} is LANE-LOCAL.
// Window 0 folds the reference's t=0 special step via lane-0 overrides
// (a_eff=1 -> lev0 = y0/s0; b_eff=0 -> "ns_0" = s0[0], which fills
// seasonalities col 24 and feeds s_24 = s0[0] for window 1).
//
// y loads: 2-deep register pipeline, UNCONDITIONAL clamped-index loads
// (no exec predication -> compiler keeps them in flight across windows;
// tail-lane duplicate loads just re-read resident lines).
__global__ __launch_bounds__(256, 8) void es_scan_kernel(
    const float* __restrict__ y,
    const int*   __restrict__ idxs,
    const float* __restrict__ lev_sms,
    const float* __restrict__ seas_sms,
    const float* __restrict__ init_seas,
    float* __restrict__ levels,
    float* __restrict__ seasout)
{
    const int tid = threadIdx.x;
    const int grp = tid >> 5;                 // 8 series per 256-thread block
    const int j   = tid & 31;                 // lane within group; j<24 active
    const int i   = blockIdx.x * 8 + grp;     // series index
    const bool act = (j < SEAS);

    const int id = idxs[i];
    const float a  = 1.0f / (1.0f + __expf(-lev_sms[id]));
    const float b  = 1.0f / (1.0f + __expf(-seas_sms[id]));
    const float ia = 1.0f - a, ib = 1.0f - b;

    // scan-round weights ia^{1,2,4,8,16} and per-lane carry weight ia^(j+1)
    const float ia1 = ia, ia2 = ia1*ia1, ia4 = ia2*ia2, ia8 = ia4*ia4, ia16 = ia8*ia8;
    const float iapow = __powf(ia, (float)(j + 1));

    const size_t lrow = (size_t)i * NT;
    const size_t srow = (size_t)i * SLEN;
    const float* yrow = y + lrow;

    // initial seasonal state s = exp(init_seas[id][j]); also emit cols 0..23
    float s = 1.0f;
    if (act) {
        s = __expf(init_seas[(size_t)id * SEAS + j]);
        seasout[srow + j] = s;
    }

    float lev_prev = 0.0f;

    // 2-deep y pipeline (loads issued 2 windows ahead of use)
    float ycur = yrow[j];                                   // w=0 (24*0+j < NT)
    float ynxt = yrow[SEAS + j];                            // w=1
    
    for (int w = 0; w < NW; ++w) {
        const int t = SEAS * w + j;
        const bool on = act && (t < NT);

        // issue load for window w+2 (clamped, unconditional)
        int tpf = SEAS * (w + 2) + j;
        tpf = tpf < NT ? tpf : NT - 1;
        const float ypf = yrow[tpf];

        // window-0 lane-0 overrides (the reference's t=0 special step)
        float ae = a, be = b, ibe = ib;
        if (w == 0 && j == 0) { ae = 1.0f; be = 0.0f; ibe = 1.0f; }

        // c_j = a*y/s, then weighted inclusive scan over lanes 0..23:
        // x_j = sum_{m<=j} ia^{j-m} c_m   (Kogge-Stone, 5 rounds)
        float x = ae * ycur * frcp(s);
        float tsh;
        tsh = __shfl_up(x, 1, 32);  if (j >= 1)  x = fmaf(ia1,  tsh, x);
        tsh = __shfl_up(x, 2, 32);  if (j >= 2)  x = fmaf(ia2,  tsh, x);
        tsh = __shfl_up(x, 4, 32);  if (j >= 4)  x = fmaf(ia4,  tsh, x);
        tsh = __shfl_up(x, 8, 32);  if (j >= 8)  x = fmaf(ia8,  tsh, x);
        tsh = __shfl_up(x, 16, 32); if (j >= 16) x = fmaf(ia16, tsh, x);

        const float lev = fmaf(iapow, lev_prev, x);          // + ia^(j+1)*carry
        const float ns  = fmaf(ibe, s, be * ycur * frcp(lev)); // seasonal update

        if (on) {
            levels[lrow + t]         = lev;  // coalesced: 24 consecutive floats
            seasout[srow + SEAS + t] = ns;   // coalesced: 24 consecutive floats
        }

        lev_prev = __shfl(lev, 23, 32);      // consumed only at END of next
        s = ns;                              //   window's scan -> overlaps it
        ycur = ynxt; ynxt = ypf;             // advance y pipeline
    }
}

extern "C" void kernel_launch(void* const* d_in, const int* in_sizes, int n_in,
                              void* d_out, int out_size, void* d_ws, size_t ws_size,
                              hipStream_t stream) {
    const float* y         = (const float*)d_in[0];
    const int*   idxs      = (const int*)d_in[1];
    const float* lev_sms   = (const float*)d_in[2];
    const float* seas_sms  = (const float*)d_in[3];
    const float* init_seas = (const float*)d_in[4];

    float* levels  = (float*)d_out;
    float* seasout = levels + (size_t)NSER * NT;

    es_scan_kernel<<<NSER/8, 256, 0, stream>>>(y, idxs, lev_sms, seas_sms, init_seas,
                                               levels, seasout);
}

// Round 7
// 251.323 us; speedup vs baseline: 1.1893x; 1.0510x over previous
//
#include <hip/hip_runtime.h>

#define NSER 65536
#define NT   1024
#define SEAS 24
#define SLEN (NT + SEAS)   // 1048 seasonal output columns
#define NW   43            // windows w=0..42; last covers t=1008..1023 (16 steps)

__device__ __forceinline__ float frcp(float x) { return __builtin_amdgcn_rcpf(x); }

// DPP move with bound_ctrl: out-of-range source lanes produce 0.0f.
// CTRL: 0x110+N = row_shr:N (within 16-lane rows), 0x142 = row_bcast15
// (lane15 -> lanes16-31, lane47 -> lanes48-63).
template<int CTRL>
__device__ __forceinline__ float dpp0(float x) {
    return __int_as_float(
        __builtin_amdgcn_update_dpp(0, __float_as_int(x), CTRL, 0xF, 0xF, true));
}

// One 32-lane group per series, lane j owns t = 24*w + j (j < 24).
// Level recurrence is linear -> weighted inclusive scan per window, done
// entirely on the VALU pipe via DPP:
//   rounds row_shr 1/2/4/8 (weights ia^1,2,4,8; shifted-in lanes get 0.0 so
//   no masks needed), then row_bcast15 adds ia^(j-15) * prefix(0..15) on
//   lanes 16..23 (weight 0 elsewhere). Window carry (lane 23's lev) moves
//   via v_readlane -> zero LDS traffic in the whole kernel.
// Window 0 folds the reference's t=0 special step via lane-0 overrides
// (a_eff=1 -> lev0=y0/s0; b_eff=0 -> "ns_0"=s0[0], filling seasonalities
// col 24 and feeding s_24 = s0[0] for window 1).
__global__ __launch_bounds__(256, 8) void es_dpp_kernel(
    const float* __restrict__ y,
    const int*   __restrict__ idxs,
    const float* __restrict__ lev_sms,
    const float* __restrict__ seas_sms,
    const float* __restrict__ init_seas,
    float* __restrict__ levels,
    float* __restrict__ seasout)
{
    const int tid = threadIdx.x;
    const int grp = tid >> 5;                 // 8 series per 256-thread block
    const int j   = tid & 31;                 // lane within group; j<24 active
    const int i   = blockIdx.x * 8 + grp;     // series index
    const bool act = (j < SEAS);

    const int id = idxs[i];
    const float a  = 1.0f / (1.0f + __expf(-lev_sms[id]));
    const float b  = 1.0f / (1.0f + __expf(-seas_sms[id]));
    const float ia = 1.0f - a, ib = 1.0f - b;

    // scan-round weights, per-lane carry weight ia^(j+1), cross-row weight
    const float ia1 = ia, ia2 = ia1*ia1, ia4 = ia2*ia2, ia8 = ia4*ia4;
    const float iapow = __powf(ia, (float)(j + 1));
    const float wbc   = (j >= 16 && j < SEAS) ? __powf(ia, (float)(j - 15)) : 0.0f;

    const size_t lrow = (size_t)i * NT;
    const size_t srow = (size_t)i * SLEN;
    const float* yrow = y + lrow;

    // initial seasonal state s = exp(init_seas[id][j]); emit cols 0..23
    float s = 1.0f;
    if (act) {
        s = __expf(init_seas[(size_t)id * SEAS + j]);
        seasout[srow + j] = s;
    }

    float lev_prev = 0.0f;

    // 2-deep y pipeline, unconditional clamped-index loads
    float ycur = yrow[j];                                   // w=0
    float ynxt = yrow[SEAS + j];                            // w=1

    for (int w = 0; w < NW; ++w) {
        const int t = SEAS * w + j;
        const bool on = act && (t < NT);

        // issue load for window w+2 (clamped, unconditional)
        int tpf = SEAS * (w + 2) + j;
        tpf = tpf < NT ? tpf : NT - 1;
        const float ypf = yrow[tpf];

        // window-0 lane-0 overrides (the reference's t=0 special step)
        float ae = a, be = b, ibe = ib;
        if (w == 0 && j == 0) { ae = 1.0f; be = 0.0f; ibe = 1.0f; }

        // weighted inclusive scan, all-VALU (DPP):
        float x = ae * ycur * frcp(s);
        x = fmaf(ia1, dpp0<0x111>(x), x);   // row_shr:1
        x = fmaf(ia2, dpp0<0x112>(x), x);   // row_shr:2
        x = fmaf(ia4, dpp0<0x114>(x), x);   // row_shr:4
        x = fmaf(ia8, dpp0<0x118>(x), x);   // row_shr:8  -> full row prefix
        x = fmaf(wbc, dpp0<0x142>(x), x);   // row_bcast15 cross-row term

        const float lev = fmaf(iapow, lev_prev, x);            // + ia^(j+1)*carry
        const float ns  = fmaf(ibe, s, be * ycur * frcp(lev)); // seasonal update

        if (on) {
            levels[lrow + t]         = lev;  // 24 consecutive floats / series
            seasout[srow + SEAS + t] = ns;
        }

        // carry: lane 23 (group A) / lane 55 (group B) -> all lanes, no LDS
        {
            const int li = __float_as_int(lev);
            const float cA = __int_as_float(__builtin_amdgcn_readlane(li, 23));
            const float cB = __int_as_float(__builtin_amdgcn_readlane(li, 55));
            lev_prev = (tid & 32) ? cB : cA;
        }
        s = ns;                              // lane-local seasonal feedback
        ycur = ynxt; ynxt = ypf;             // advance y pipeline
    }
}

extern "C" void kernel_launch(void* const* d_in, const int* in_sizes, int n_in,
                              void* d_out, int out_size, void* d_ws, size_t ws_size,
                              hipStream_t stream) {
    const float* y         = (const float*)d_in[0];
    const int*   idxs      = (const int*)d_in[1];
    const float* lev_sms   = (const float*)d_in[2];
    const float* seas_sms  = (const float*)d_in[3];
    const float* init_seas = (const float*)d_in[4];

    float* levels  = (float*)d_out;
    float* seasout = levels + (size_t)NSER * NT;

    es_dpp_kernel<<<NSER/8, 256, 0, stream>>>(y, idxs, lev_sms, seas_sms, init_seas,
                                              levels, seasout);
}

// Round 9
// 192.194 us; speedup vs baseline: 1.5552x; 1.3077x over previous
//
#include <hip/hip_runtime.h>

#define NSER 65536
#define NT   1024
#define SEAS 24
#define SLEN (NT + SEAS)   // 1048 seasonal output columns
#define NSB  10            // superblocks of 4 windows (96 steps): t = 0..959
#define LST  104           // LDS row stride (96 data + 8 pad)

__device__ __forceinline__ float frcp(float x) { return __builtin_amdgcn_rcpf(x); }

// DPP move; bound_ctrl=1 -> out-of-range sources read 0.0f; lanes whose row is
// masked out of RMASK receive the OLD operand (0.0f here).
// 0x110+N = row_shr:N (16-lane rows); 0x142 = row_bcast15 (15->16..31,
// 31->32..47, 47->48..63 — RMASK=0xA keeps only rows 1,3 so the lane31->
// group-B path is severed structurally).
template<int CTRL, int RMASK = 0xF>
__device__ __forceinline__ float dpp0(float x) {
    return __int_as_float(
        __builtin_amdgcn_update_dpp(0, __float_as_int(x), CTRL, RMASK, 0xF, true));
}

// One 32-lane group per series, lane j owns t = 24*w + j (j < 24).
// Weighted inclusive scan per window entirely on the VALU via DPP (round 7).
// 4-window superblocks (96 contiguous floats per series per array) staged
// through wave-private LDS so ALL main-loop VMEM is full-line float4:
// per superblock per wave 3 VMEM instructions (768 B each) instead of 12
// partial-line ones. No barriers anywhere (wave-private LDS, lgkmcnt only).
__global__ __launch_bounds__(256, 8) void es_dpp4_kernel(
    const float* __restrict__ y,
    const int*   __restrict__ idxs,
    const float* __restrict__ lev_sms,
    const float* __restrict__ seas_sms,
    const float* __restrict__ init_seas,
    float* __restrict__ levels,
    float* __restrict__ seasout)
{
    __shared__ float ybuf [8][LST];
    __shared__ float lvbuf[8][LST];
    __shared__ float nsbuf[8][LST];

    const int tid = threadIdx.x;
    const int grp = tid >> 5;                 // 8 series per 256-thread block
    const int j   = tid & 31;                 // lane within group; j<24 active
    const int i   = blockIdx.x * 8 + grp;     // series index
    const bool act = (j < SEAS);

    // one-time pad init: inactive lanes' transpose reads (indices 96..103)
    // must be finite (they are never written by the staging path)
    if (!act) ybuf[grp][72 + j] = 1.0f;       // 72+24..72+31 = 96..103

    const int id = idxs[i];
    const float a  = 1.0f / (1.0f + __expf(-lev_sms[id]));
    const float b  = 1.0f / (1.0f + __expf(-seas_sms[id]));
    const float ia = 1.0f - a, ib = 1.0f - b;

    const float ia1 = ia, ia2 = ia1*ia1, ia4 = ia2*ia2, ia8 = ia4*ia4;
    const float iapow = __powf(ia, (float)(j + 1));
    const float wbc   = (j >= 16 && j < SEAS) ? __powf(ia, (float)(j - 15)) : 0.0f;

    const size_t lrow = (size_t)i * NT;
    const size_t srow = (size_t)i * SLEN;
    const float* yrow = y + lrow;

    // initial seasonal state s = exp(init_seas[id][j]); emit cols 0..23
    float s = 1.0f;
    if (act) {
        s = __expf(init_seas[(size_t)id * SEAS + j]);
        seasout[srow + j] = s;
    }

    float lev_prev = 0.0f;

    // per-window scan core (DPP, all-VALU; carry via readlane)
    auto window = [&](float ycur, float ae, float be, float ibe) -> float2 {
        float x = ae * ycur * frcp(s);
        x = fmaf(ia1, dpp0<0x111>(x), x);          // row_shr:1
        x = fmaf(ia2, dpp0<0x112>(x), x);          // row_shr:2
        x = fmaf(ia4, dpp0<0x114>(x), x);          // row_shr:4
        x = fmaf(ia8, dpp0<0x118>(x), x);          // row_shr:8
        x = fmaf(wbc, dpp0<0x142, 0xA>(x), x);     // row_bcast15, rows 1&3 only
        const float lev = fmaf(iapow, lev_prev, x);
        const float ns  = fmaf(ibe, s, be * ycur * frcp(lev));
        const int li = __float_as_int(lev);
        const float cA = __int_as_float(__builtin_amdgcn_readlane(li, 23));
        const float cB = __int_as_float(__builtin_amdgcn_readlane(li, 55));
        lev_prev = (tid & 32) ? cB : cA;
        s = ns;
        return make_float2(lev, ns);
    };

    // prefetch superblock 0's y: lane l<24 loads y[4l .. 4l+3]
    float4 ypf = make_float4(1.f, 1.f, 1.f, 1.f);
    if (act) ypf = *(const float4*)(yrow + 4 * j);

    for (int u = 0; u < NSB; ++u) {
        // stage current superblock's y into LDS (wave-private; lgkmcnt only)
        if (act) *(float4*)&ybuf[grp][4 * j] = ypf;

        // prefetch next superblock's y (full-line, independent of this block)
        if (u + 1 < NSB) {
            if (act) ypf = *(const float4*)(yrow + 96 * (u + 1) + 4 * j);
        }

        const bool first = (u == 0);
        #pragma unroll
        for (int k = 0; k < 4; ++k) {
            const float ycur = ybuf[grp][24 * k + j];   // ds_read_b32 transpose
            float ae = a, be = b, ibe = ib;
            if (first && k == 0 && j == 0) { ae = 1.0f; be = 0.0f; ibe = 1.0f; }
            const float2 r = window(ycur, ae, be, ibe);
            lvbuf[grp][24 * k + j] = r.x;
            nsbuf[grp][24 * k + j] = r.y;
        }

        // flush: full-line float4 stores (384 B contiguous per series per array)
        if (act) {
            const float4 lvv = *(float4*)&lvbuf[grp][4 * j];
            const float4 nsv = *(float4*)&nsbuf[grp][4 * j];
            *(float4*)(levels  + lrow + 96 * u + 4 * j)        = lvv;
            *(float4*)(seasout + srow + SEAS + 96 * u + 4 * j) = nsv;
        }
    }

    // tail: windows w = 40,41,42 (t = 960..1023), scalar path
    for (int w = 40; w < 43; ++w) {
        const int t = SEAS * w + j;
        const bool on = act && (t < NT);
        float yt = 1.0f;
        if (on) yt = yrow[t];
        const float2 r = window(yt, a, b, ib);
        if (on) {
            levels[lrow + t]         = r.x;
            seasout[srow + SEAS + t] = r.y;
        }
    }
}

extern "C" void kernel_launch(void* const* d_in, const int* in_sizes, int n_in,
                              void* d_out, int out_size, void* d_ws, size_t ws_size,
                              hipStream_t stream) {
    const float* y         = (const float*)d_in[0];
    const int*   idxs      = (const int*)d_in[1];
    const float* lev_sms   = (const float*)d_in[2];
    const float* seas_sms  = (const float*)d_in[3];
    const float* init_seas = (const float*)d_in[4];

    float* levels  = (float*)d_out;
    float* seasout = levels + (size_t)NSER * NT;

    es_dpp4_kernel<<<NSER/8, 256, 0, stream>>>(y, idxs, lev_sms, seas_sms, init_seas,
                                               levels, seasout);
}

// Round 11
// 140.939 us; speedup vs baseline: 2.1208x; 1.3637x over previous
//
#include <hip/hip_runtime.h>

#define NSER 65536
#define NT   1024
#define SEAS 24
#define SLEN (NT + SEAS)   // 1048 seasonal output columns
#define NSB  10            // main superblocks of 4 windows (96 steps): t = 0..959
#define LST  104           // LDS row stride (96 data + 8 pad)

typedef float v4f __attribute__((ext_vector_type(4)));  // native vector type:
// required by __builtin_nontemporal_* (HIP_vector_type float4 is rejected)

__device__ __forceinline__ float frcp(float x) { return __builtin_amdgcn_rcpf(x); }

// DPP move; bound_ctrl=1 -> out-of-range sources read 0.0f; rows masked out of
// RMASK receive the OLD operand (0.0f).  0x110+N = row_shr:N (16-lane rows);
// 0x142 = row_bcast15 (15->16..31, 31->32..47, 47->48..63 — RMASK=0xA keeps
// rows 1,3 only, severing the lane31 -> group-B path structurally).
template<int CTRL, int RMASK = 0xF>
__device__ __forceinline__ float dpp0(float x) {
    return __int_as_float(
        __builtin_amdgcn_update_dpp(0, __float_as_int(x), CTRL, RMASK, 0xF, true));
}

// One 32-lane group per series, lane j owns t = 24*w + j (j < 24).
// Weighted inclusive scan per window on the VALU via DPP; carry via readlane.
// 4-window superblocks staged through wave-private LDS: all main VMEM is
// full-line v4f (nt load for y, nt store for levels; seasout normal so its
// misaligned edge lines merge in L2). Tail (t=960..1023) staged the same way.
__global__ __launch_bounds__(256, 8) void es_dpp5_kernel(
    const float* __restrict__ y,
    const int*   __restrict__ idxs,
    const float* __restrict__ lev_sms,
    const float* __restrict__ seas_sms,
    const float* __restrict__ init_seas,
    float* __restrict__ levels,
    float* __restrict__ seasout)
{
    __shared__ float ybuf [8][LST];
    __shared__ float lvbuf[8][LST];
    __shared__ float nsbuf[8][LST];

    const int tid = threadIdx.x;
    const int grp = tid >> 5;                 // 8 series per 256-thread block
    const int j   = tid & 31;                 // lane within group; j<24 active
    const int i   = blockIdx.x * 8 + grp;     // series index
    const bool act = (j < SEAS);

    // pad init: indices 96..103 (read by lanes j>=24 in main window k=3)
    if (!act) ybuf[grp][72 + j] = 1.0f;

    const int id = idxs[i];
    const float a  = 1.0f / (1.0f + __expf(-lev_sms[id]));
    const float b  = 1.0f / (1.0f + __expf(-seas_sms[id]));
    const float ia = 1.0f - a, ib = 1.0f - b;

    const float ia1 = ia, ia2 = ia1*ia1, ia4 = ia2*ia2, ia8 = ia4*ia4;
    const float iapow = __powf(ia, (float)(j + 1));
    const float wbc   = (j >= 16 && j < SEAS) ? __powf(ia, (float)(j - 15)) : 0.0f;

    const size_t lrow = (size_t)i * NT;
    const size_t srow = (size_t)i * SLEN;
    const float* yrow = y + lrow;

    // initial seasonal state s = exp(init_seas[id][j]); emit cols 0..23
    float s = 1.0f;
    if (act) {
        s = __expf(init_seas[(size_t)id * SEAS + j]);
        seasout[srow + j] = s;
    }

    float lev_prev = 0.0f;

    // per-window scan core (DPP, all-VALU; carry via readlane)
    auto window = [&](float ycur, float ae, float be, float ibe) -> float2 {
        float x = ae * ycur * frcp(s);
        x = fmaf(ia1, dpp0<0x111>(x), x);          // row_shr:1
        x = fmaf(ia2, dpp0<0x112>(x), x);          // row_shr:2
        x = fmaf(ia4, dpp0<0x114>(x), x);          // row_shr:4
        x = fmaf(ia8, dpp0<0x118>(x), x);          // row_shr:8
        x = fmaf(wbc, dpp0<0x142, 0xA>(x), x);     // row_bcast15, rows 1&3 only
        const float lev = fmaf(iapow, lev_prev, x);
        const float ns  = fmaf(ibe, s, be * ycur * frcp(lev));
        const int li = __float_as_int(lev);
        const float cA = __int_as_float(__builtin_amdgcn_readlane(li, 23));
        const float cB = __int_as_float(__builtin_amdgcn_readlane(li, 55));
        lev_prev = (tid & 32) ? cB : cA;
        s = ns;
        return make_float2(lev, ns);
    };

    // prefetch superblock 0's y: lane j<24 loads y[4j .. 4j+3]
    v4f ypf = (v4f){1.f, 1.f, 1.f, 1.f};
    if (act) ypf = __builtin_nontemporal_load((const v4f*)(yrow + 4 * j));

    for (int u = 0; u < NSB; ++u) {
        // stage current superblock's y (wave-private LDS; lgkmcnt only)
        if (act) *(v4f*)&ybuf[grp][4 * j] = ypf;

        // prefetch next batch: main superblock u+1, or the 64-float tail
        if (u + 1 < NSB) {
            if (act)
                ypf = __builtin_nontemporal_load(
                    (const v4f*)(yrow + 96 * (u + 1) + 4 * j));
        } else {
            if (j < 16)
                ypf = __builtin_nontemporal_load((const v4f*)(yrow + 960 + 4 * j));
        }

        const bool first = (u == 0);
        #pragma unroll
        for (int k = 0; k < 4; ++k) {
            const float ycur = ybuf[grp][24 * k + j];   // ds_read transpose
            float ae = a, be = b, ibe = ib;
            if (first && k == 0 && j == 0) { ae = 1.0f; be = 0.0f; ibe = 1.0f; }
            const float2 r = window(ycur, ae, be, ibe);
            lvbuf[grp][24 * k + j] = r.x;
            nsbuf[grp][24 * k + j] = r.y;
        }

        // flush: full-line v4f (384 B contiguous per series per array)
        if (act) {
            const v4f lvv = *(v4f*)&lvbuf[grp][4 * j];
            const v4f nsv = *(v4f*)&nsbuf[grp][4 * j];
            __builtin_nontemporal_store(lvv, (v4f*)(levels + lrow + 96 * u + 4 * j));
            *(v4f*)(seasout + srow + SEAS + 96 * u + 4 * j) = nsv;
        }
    }

    // ---- staged tail: t = 960..1023 (windows 40,41 full + 42 = 16 steps) ----
    if (j < 16) *(v4f*)&ybuf[grp][4 * j] = ypf;      // stage 64 floats (0..63)
    else        ybuf[grp][48 + j] = 1.0f;            // pad 64..79 finite

    #pragma unroll
    for (int k = 0; k < 3; ++k) {
        const float ycur = ybuf[grp][24 * k + j];
        const float2 r = window(ycur, a, b, ib);
        lvbuf[grp][24 * k + j] = r.x;   // k=2, j>=16 lands at 64..79 (unused)
        nsbuf[grp][24 * k + j] = r.y;
    }

    if (j < 16) {
        const v4f lvv = *(v4f*)&lvbuf[grp][4 * j];
        const v4f nsv = *(v4f*)&nsbuf[grp][4 * j];
        __builtin_nontemporal_store(lvv, (v4f*)(levels + lrow + 960 + 4 * j));
        *(v4f*)(seasout + srow + SEAS + 960 + 4 * j) = nsv;
    }
}

extern "C" void kernel_launch(void* const* d_in, const int* in_sizes, int n_in,
                              void* d_out, int out_size, void* d_ws, size_t ws_size,
                              hipStream_t stream) {
    const float* y         = (const float*)d_in[0];
    const int*   idxs      = (const int*)d_in[1];
    const float* lev_sms   = (const float*)d_in[2];
    const float* seas_sms  = (const float*)d_in[3];
    const float* init_seas = (const float*)d_in[4];

    float* levels  = (float*)d_out;
    float* seasout = levels + (size_t)NSER * NT;

    es_dpp5_kernel<<<NSER/8, 256, 0, stream>>>(y, idxs, lev_sms, seas_sms, init_seas,
                                               levels, seasout);
}